// Round 5
// baseline (692.357 us; speedup 1.0000x reference)
//
#include <hip/hip_runtime.h>
#include <cstdint>
#include <cstddef>

// Problem constants (fixed by the reference)
#define S_TOK   8192
#define DMODEL  2048
#define NEXP    64
#define CAP     128
#define COMBINE_ELEMS 67108864ULL            // 8192*64*128
#define OUT_ELEMS     134217793ULL           // 1 + 2*COMBINE + 64
#define OUT_F4        33554448ULL            // floor(OUT_ELEMS/4); covers [0, 134217792)
#define MAXN 2048

// ws layout (float offsets)
#define WS_TOKE   0        // int   [8192]
#define WS_TGATE  8192     // float [8192]
#define WS_TNOI   16384    // float [8192]
#define WS_MEP    24576    // float [256*64]
#define WS_LAUX   40960    // float [1]
#define WS_CNTS   41024    // float [64]
#define WS_SELC   41088    // int   [64]
#define WS_SELT   41152    // int   [64*128]
#define WS_SELL   49344    // int   [64*128]

// jax.random.uniform(key(42)): JAX >= 0.5 threefry_partitionable path:
// bits[idx] = o0 ^ o1 of threefry2x32((0,42), (0, idx))
__device__ __forceinline__ unsigned rotl32(unsigned x, unsigned r) {
    return (x << r) | (x >> (32u - r));
}

__device__ __forceinline__ void threefry2x32(unsigned k0, unsigned k1,
                                             unsigned c0, unsigned c1,
                                             unsigned& o0, unsigned& o1) {
    unsigned ks[3] = {k0, k1, k0 ^ k1 ^ 0x1BD11BDAu};
    unsigned x0 = c0 + ks[0];
    unsigned x1 = c1 + ks[1];
    const unsigned rotA[4] = {13u, 15u, 26u, 6u};
    const unsigned rotB[4] = {17u, 29u, 16u, 24u};
#pragma unroll
    for (int i = 0; i < 5; ++i) {
        const unsigned* rr = (i & 1) ? rotB : rotA;
#pragma unroll
        for (int j = 0; j < 4; ++j) {
            x0 += x1;
            x1 = rotl32(x1, rr[j]);
            x1 ^= x0;
        }
        x0 += ks[(i + 1) % 3];
        x1 += ks[(i + 2) % 3] + (unsigned)(i + 1);
    }
    o0 = x0; o1 = x1;
}

__device__ __forceinline__ float jax_uniform_noise(unsigned idx) {
    unsigned o0, o1;
    threefry2x32(0u, 42u, 0u, idx, o0, o1);
    unsigned bits = o0 ^ o1;
    unsigned fb = (bits >> 9) | 0x3f800000u;
    float f;
    __builtin_memcpy(&f, &fb, 4);
    return f - 1.0f;
}

// ------ Kernel 1: logits GEMM + softmax/argmax (verified bit-exact, R2/R3) ------
// Runs ALONE so its x-reads (64 MB HBM stream) never mix with the output fill.
#define GEMM_BLOCKS 256
__global__ __launch_bounds__(128) void gemm_softmax(const float* __restrict__ x,
                                                    const float* __restrict__ wg,
                                                    int* __restrict__ tok_expert,
                                                    float* __restrict__ tok_gate,
                                                    float* __restrict__ tok_noise,
                                                    float* __restrict__ me_part) {
    __shared__ __align__(16) float xs[32][68];   // doubles as logits tile post-GEMM
    __shared__ __align__(16) float wsh[64][68];
    __shared__ float mep[2][64];
    const int tid = threadIdx.x;
    const int s0 = blockIdx.x * 32;
    const int g  = tid & 15;          // experts g, g+16, g+32, g+48
    const int ty = tid >> 4;          // tokens ty*4 .. ty*4+3
    float acc[4][4];
#pragma unroll
    for (int i = 0; i < 4; ++i)
#pragma unroll
        for (int j = 0; j < 4; ++j) acc[i][j] = 0.f;

    for (int k0 = 0; k0 < DMODEL; k0 += 64) {
#pragma unroll
        for (int i = 0; i < 4; ++i) {  // x chunk: 32x64 = 512 float4, 128 thr
            int slot = tid + i * 128;
            int r = slot >> 4, c4 = (slot & 15) * 4;
            float4 v = *(const float4*)&x[(size_t)(s0 + r) * DMODEL + k0 + c4];
            *(float4*)&xs[r][c4] = v;
        }
#pragma unroll
        for (int i = 0; i < 8; ++i) {  // wg chunk: 64x64 = 1024 float4
            int slot = tid + i * 128;
            int r = slot >> 4, c4 = (slot & 15) * 4;
            float4 v = *(const float4*)&wg[(size_t)r * DMODEL + k0 + c4];
            *(float4*)&wsh[r][c4] = v;
        }
        __syncthreads();
#pragma unroll
        for (int k4 = 0; k4 < 64; k4 += 4) {
            float4 xv[4], wv[4];
#pragma unroll
            for (int t = 0; t < 4; ++t) xv[t] = *(float4*)&xs[ty * 4 + t][k4];
#pragma unroll
            for (int j = 0; j < 4; ++j) wv[j] = *(float4*)&wsh[g + 16 * j][k4];
#pragma unroll
            for (int t = 0; t < 4; ++t)
#pragma unroll
                for (int j = 0; j < 4; ++j) {
                    // k-ascending chain per output: bit-identical across rounds
                    acc[t][j] += xv[t].x * wv[j].x; acc[t][j] += xv[t].y * wv[j].y;
                    acc[t][j] += xv[t].z * wv[j].z; acc[t][j] += xv[t].w * wv[j].w;
                }
        }
        __syncthreads();
    }

    // ---- in-block softmax: park logits tile in xs (all xs reads are done) ----
#pragma unroll
    for (int t = 0; t < 4; ++t)
#pragma unroll
        for (int j = 0; j < 4; ++j)
            xs[ty * 4 + t][g + 16 * j] = acc[t][j];
    __syncthreads();

    const int lane = tid & 63;        // lane == expert
    const int w = tid >> 6;           // wave handles tokens w*16 .. w*16+15
    float me_acc = 0.f;
#pragma unroll
    for (int it = 0; it < 16; ++it) {
        const int trow = w * 16 + it;
        float v = xs[trow][lane];
        float m = v;
#pragma unroll
        for (int off = 32; off; off >>= 1) m = fmaxf(m, __shfl_xor(m, off));
        float ev = expf(v - m);
        float sum = ev;
#pragma unroll
        for (int off = 32; off; off >>= 1) sum += __shfl_xor(sum, off);
        float gate = ev / sum;
        me_acc += gate;

        float bv = gate; int bi = lane;
#pragma unroll
        for (int off = 32; off; off >>= 1) {
            float ov = __shfl_xor(bv, off);
            int   oi = __shfl_xor(bi, off);
            if (ov > bv || (ov == bv && oi < bi)) { bv = ov; bi = oi; }
        }
        if (lane == 0) {
            const int s = s0 + trow;
            tok_expert[s] = bi;
            tok_gate[s]   = bv;
            tok_noise[s]  = jax_uniform_noise((unsigned)(s * NEXP + bi));
        }
    }
    mep[w][lane] = me_acc;
    __syncthreads();
    if (tid < 64)
        me_part[(size_t)blockIdx.x * 64 + tid] = mep[0][tid] + mep[1][tid];
}

// ------ Kernel 2: PURE-WRITE fill + select/finalize staged to ws ------
// blockIdx 0..63  : per-expert select (reads ~1 MB of L2-hot ws -> negligible
//                   read-mix), stages (token, slot) lists to ws. Hidden under fill.
// blockIdx 64     : finalize: LDS histogram + serial me_part reduce (bit-exact);
//                   stages l_aux + counts to ws.
// blockIdx 65+    : fill: 2048 blocks x 256 thr grid-stride float4 zeros --
//                   fillBufferAligned's exact config (8 blocks/CU, 32 waves/CU,
//                   which sustains 6.2 TB/s on this chip when writes are PURE).
//                   LDS shrunk to 16.4 KB (ushort toks/rnk) so residency = 8/CU.
#define SELF_BLOCKS (NEXP + 1)               // 65
#define FILLB 2048
struct SMemS { float noi[MAXN]; unsigned short toks[MAXN]; unsigned short rnk[MAXN]; int n; };
struct SMemF { int hist[NEXP]; };
union __align__(16) SMemU { SMemS s; SMemF f; };

__global__ __launch_bounds__(256) void fill_select(float* __restrict__ ws,
                                                   float* __restrict__ d_out) {
    __shared__ SMemU sm;
    const int tid = threadIdx.x;
    const unsigned bid = blockIdx.x;

    // ---------------- fill role: pure-write sweep ----------------
    if (bid >= SELF_BLOCKS) {
        float4* o4 = (float4*)d_out;
        const float4 z = {0.f, 0.f, 0.f, 0.f};
        const size_t t0 = (size_t)(bid - SELF_BLOCKS) * 256 + tid;
        const size_t stride = (size_t)FILLB * 256;
        for (size_t i = t0; i < OUT_F4; i += stride)   // 64 iters/thread
            o4[i] = z;
        // elements [OUT_F4*4, OUT_ELEMS) = the last exp_count slot: k3 writes it.
        return;
    }

    const int*   tok_expert = (const int*)(ws + WS_TOKE);
    const float* tok_noise  = ws + WS_TNOI;
    const float* me_part    = ws + WS_MEP;

    if (bid == NEXP) {                 // ---- finalize: stage to ws ----
        if (tid < NEXP) sm.f.hist[tid] = 0;
        __syncthreads();
        for (int s = tid; s < S_TOK; s += 256)
            atomicAdd(&sm.f.hist[tok_expert[s]], 1);
        __syncthreads();
        if (tid < 64) {
            const int e = tid;
            float me = 0.f;
            for (int b = 0; b < GEMM_BLOCKS; ++b) me += me_part[(size_t)b * 64 + e];  // serial: bit-exact
            me /= (float)S_TOK;
            int c = sm.f.hist[e];
            ws[WS_CNTS + e] = (float)c;
            float p = me * ((float)c / (float)S_TOK);
#pragma unroll
            for (int off = 32; off; off >>= 1) p += __shfl_xor(p, off);
            if (e == 0) ws[WS_LAUX] = p * (float)NEXP;
        }
        return;
    }

    // ---- per-expert top-capacity select: stage (token, slot) lists to ws ----
    const int e = (int)bid;
    int* sel_cnt = (int*)(ws + WS_SELC);
    int* sel_tok = (int*)(ws + WS_SELT) + e * CAP;
    int* sel_loc = (int*)(ws + WS_SELL) + e * CAP;

    if (tid == 0) sm.s.n = 0;
    __syncthreads();

    for (int s = tid; s < S_TOK; s += 256) {
        if (tok_expert[s] == e) {
            int i = atomicAdd(&sm.s.n, 1);
            if (i < MAXN) { sm.s.toks[i] = (unsigned short)s; sm.s.noi[i] = tok_noise[s]; }
        }
    }
    __syncthreads();
    int n = sm.s.n; if (n > MAXN) n = MAXN;

    // rank by noise desc, ties -> lower token index (lax.top_k stability)
    for (int i = tid; i < n; i += 256) {
        float vi = sm.s.noi[i]; int si = sm.s.toks[i];
        int r = 0;
        for (int j = 0; j < n; ++j) {
            float vj = sm.s.noi[j];
            r += (vj > vi) || (vj == vi && (int)sm.s.toks[j] < si);
        }
        sm.s.rnk[i] = (unsigned short)r;
    }
    __syncthreads();

    for (int i = tid; i < n; i += 256) {
        if (sm.s.rnk[i] < CAP) {
            int si = sm.s.toks[i];
            int loc = 0;  // cumsum slot among kept tokens, by token index
            for (int j = 0; j < n; ++j)
                loc += (sm.s.rnk[j] < CAP) && ((int)sm.s.toks[j] < si);
            // kept tokens have distinct rnk < CAP -> rank is a collision-free index
            sel_tok[sm.s.rnk[i]] = si;
            sel_loc[sm.s.rnk[i]] = loc;
        }
    }
    if (tid == 0) sel_cnt[e] = (n < CAP) ? n : CAP;
}

// ---- Kernel 3: tiny tail after the fill: scatter + head/tail writes (R4-verified) ----
__global__ __launch_bounds__(128) void moe_scatter(const float* __restrict__ ws,
                                                   float* __restrict__ d_out) {
    const int tid = threadIdx.x;
    const int e = blockIdx.x;
    const float* tok_gate = ws + WS_TGATE;

    if (e == NEXP) {
        if (tid < 64) d_out[1 + 2 * COMBINE_ELEMS + tid] = ws[WS_CNTS + tid];
        if (tid == 0) d_out[0] = ws[WS_LAUX];
        return;
    }

    const int m = ((const int*)(ws + WS_SELC))[e];
    const int* sel_tok = (const int*)(ws + WS_SELT) + e * CAP;
    const int* sel_loc = (const int*)(ws + WS_SELL) + e * CAP;
    for (int k = tid; k < m; k += 128) {
        int si  = sel_tok[k];
        int loc = sel_loc[k];
        size_t base = 1ULL + (((size_t)si * NEXP + e) * CAP + (size_t)loc);
        d_out[base] = tok_gate[si];              // combine_weights
        d_out[base + COMBINE_ELEMS] = 1.0f;      // dispatch_mask
    }
}

extern "C" void kernel_launch(void* const* d_in, const int* in_sizes, int n_in,
                              void* d_out, int out_size, void* d_ws, size_t ws_size,
                              hipStream_t stream) {
    const float* x  = (const float*)d_in[0];
    const float* wg = (const float*)d_in[1];
    float* out = (float*)d_out;
    float* ws  = (float*)d_ws;

    int*   tok_expert = (int*)(ws + WS_TOKE);
    float* tok_gate   = ws + WS_TGATE;
    float* tok_noise  = ws + WS_TNOI;
    float* me_part    = ws + WS_MEP;

    // k1: GEMM+softmax alone (pure-read phase).
    gemm_softmax<<<GEMM_BLOCKS, 128, 0, stream>>>(x, wg, tok_expert, tok_gate,
                                                  tok_noise, me_part);
    // k2: pure-write fill + select/finalize staged to ws (reads are L2-hot ws only).
    fill_select<<<SELF_BLOCKS + FILLB, 256, 0, stream>>>(ws, out);
    // k3: sparse scatter over the zeroed output.
    moe_scatter<<<NEXP + 1, 128, 0, stream>>>(ws, out);
}

// Round 6
// 678.006 us; speedup vs baseline: 1.0212x; 1.0212x over previous
//
#include <hip/hip_runtime.h>
#include <cstdint>
#include <cstddef>

// Problem constants (fixed by the reference)
#define S_TOK   8192
#define DMODEL  2048
#define NEXP    64
#define CAP     128
#define COMBINE_ELEMS 67108864ULL            // 8192*64*128
#define OUT_ELEMS     134217793ULL           // 1 + 2*COMBINE + 64
#define OUT_F4        33554448ULL            // floor(OUT_ELEMS/4); tail elem 134217792
#define MAXN 2048

// Grid roles (k1). R3's verified-651 config preserved EXACTLY for GEMM+fill;
// 65 select/finalize blocks appended at the HIGHEST ids: with 4417 fill/GEMM
// blocks ahead of them and ~1536-2048 resident slots, they are scheduled only
// after ~2/3 of the fill has retired -- long after GEMM is done. Their
// GEMM-done spin is therefore ~0 iterations and their ~1 MB of L2-hot ws
// reads cannot disturb the fill (unlike R4, where select entered early and
// the fill grid itself was restructured -- that cost +32 us).
// d_out fill BW is pinned at ~3.2 TB/s regardless of store type / pattern /
// residency / read-mixing / runtime-memset (R0-R5 evidence): buffer property.
#define GEMM_BLOCKS 256
#define ZERO_BLOCKS 4096
#define CHUNK_F4    8192ULL                  // f4 per zero block (128 KB)
#define SEL_BASE    (GEMM_BLOCKS + ZERO_BLOCKS)      // 4352
#define FIN_BLOCK   (SEL_BASE + NEXP)                // 4416
#define TOTAL_BLOCKS (FIN_BLOCK + 1)                 // 4417

// ws layout (float offsets)
#define WS_CTR    0        // unsigned ctr[2] + pad (64 floats)
#define WS_TOKE   64       // int   [8192]
#define WS_TGATE  8256     // float [8192]
#define WS_TNOI   16448    // float [8192]
#define WS_MEP    24640    // float [256*64]
#define WS_LAUX   41024    // float [1]
#define WS_CNTS   41088    // float [64]
#define WS_SELC   41152    // int   [64]
#define WS_SELT   41216    // int   [64*128]
#define WS_SELL   49408    // int   [64*128]

// jax.random.uniform(key(42)): JAX >= 0.5 threefry_partitionable path:
// bits[idx] = o0 ^ o1 of threefry2x32((0,42), (0, idx))
__device__ __forceinline__ unsigned rotl32(unsigned x, unsigned r) {
    return (x << r) | (x >> (32u - r));
}

__device__ __forceinline__ void threefry2x32(unsigned k0, unsigned k1,
                                             unsigned c0, unsigned c1,
                                             unsigned& o0, unsigned& o1) {
    unsigned ks[3] = {k0, k1, k0 ^ k1 ^ 0x1BD11BDAu};
    unsigned x0 = c0 + ks[0];
    unsigned x1 = c1 + ks[1];
    const unsigned rotA[4] = {13u, 15u, 26u, 6u};
    const unsigned rotB[4] = {17u, 29u, 16u, 24u};
#pragma unroll
    for (int i = 0; i < 5; ++i) {
        const unsigned* rr = (i & 1) ? rotB : rotA;
#pragma unroll
        for (int j = 0; j < 4; ++j) {
            x0 += x1;
            x1 = rotl32(x1, rr[j]);
            x1 ^= x0;
        }
        x0 += ks[(i + 1) % 3];
        x1 += ks[(i + 2) % 3] + (unsigned)(i + 1);
    }
    o0 = x0; o1 = x1;
}

__device__ __forceinline__ float jax_uniform_noise(unsigned idx) {
    unsigned o0, o1;
    threefry2x32(0u, 42u, 0u, idx, o0, o1);
    unsigned bits = o0 ^ o1;
    unsigned fb = (bits >> 9) | 0x3f800000u;
    float f;
    __builtin_memcpy(&f, &fb, 4);
    return f - 1.0f;
}

// Role-dependent LDS; union keeps footprint at the GEMM role's 26,624 B
// (same occupancy as the verified R3 kernel: 6 blocks/CU).
struct SMemG { float xs[32][68]; float wsh[64][68]; float mep[2][64]; };
struct SMemS { int toks[MAXN]; float noi[MAXN]; int rnk[MAXN]; int n; };
struct SMemF { int hist[NEXP]; };
union __align__(16) SMem { SMemG g; SMemS s; SMemF f; };

__device__ __forceinline__ void wait_ctr(const unsigned* __restrict__ p, unsigned target) {
    // one poller per block; by schedule position this loop should exit immediately.
    if (threadIdx.x == 0) {
        while (__hip_atomic_load(p, __ATOMIC_RELAXED, __HIP_MEMORY_SCOPE_AGENT) < target)
            __builtin_amdgcn_s_sleep(64);
        __threadfence();   // acquire: invalidate stale caches before data reads
    }
    __syncthreads();
}

__global__ __launch_bounds__(128) void moe_k1(const float* __restrict__ x,
                                              const float* __restrict__ wg,
                                              float* __restrict__ ws,
                                              float* __restrict__ d_out) {
    __shared__ SMem sm;
    const int tid = threadIdx.x;
    const unsigned bid = blockIdx.x;

    unsigned* ctr     = (unsigned*)(ws + WS_CTR);
    int*   tok_expert = (int*)(ws + WS_TOKE);
    float* tok_gate   = ws + WS_TGATE;
    float* tok_noise  = ws + WS_TNOI;
    float* me_part    = ws + WS_MEP;

    // ---------------- fill role: R3's verified contiguous-chunk sweep ----------------
    if (bid >= GEMM_BLOCKS && bid < SEL_BASE) {
        const size_t zb = bid - GEMM_BLOCKS;
        float4* o4 = (float4*)d_out;
        const float4 z = {0.f, 0.f, 0.f, 0.f};
        const size_t lo = zb * CHUNK_F4;
        const size_t hi = (zb == ZERO_BLOCKS - 1) ? OUT_F4 : (zb + 1) * CHUNK_F4;
        for (size_t i = lo + tid; i < hi; i += 128)
            o4[i] = z;
        if (zb == ZERO_BLOCKS - 1 && tid == 0) d_out[OUT_ELEMS - 1] = 0.f;
        return;
    }

    // ---------------- GEMM + softmax role (R3 verified, + release) ----------------
    if (bid < GEMM_BLOCKS) {
        const int s0 = bid * 32;
        const int g  = tid & 15;          // experts g, g+16, g+32, g+48
        const int ty = tid >> 4;          // tokens ty*4 .. ty*4+3
        float acc[4][4];
#pragma unroll
        for (int i = 0; i < 4; ++i)
#pragma unroll
            for (int j = 0; j < 4; ++j) acc[i][j] = 0.f;

        for (int k0 = 0; k0 < DMODEL; k0 += 64) {
#pragma unroll
            for (int i = 0; i < 4; ++i) {  // x chunk: 32x64 = 512 float4
                int slot = tid + i * 128;
                int r = slot >> 4, c4 = (slot & 15) * 4;
                float4 v = *(const float4*)&x[(size_t)(s0 + r) * DMODEL + k0 + c4];
                *(float4*)&sm.g.xs[r][c4] = v;
            }
#pragma unroll
            for (int i = 0; i < 8; ++i) {  // wg chunk: 64x64 = 1024 float4
                int slot = tid + i * 128;
                int r = slot >> 4, c4 = (slot & 15) * 4;
                float4 v = *(const float4*)&wg[(size_t)r * DMODEL + k0 + c4];
                *(float4*)&sm.g.wsh[r][c4] = v;
            }
            __syncthreads();
#pragma unroll
            for (int k4 = 0; k4 < 64; k4 += 4) {
                float4 xv[4], wv[4];
#pragma unroll
                for (int t = 0; t < 4; ++t) xv[t] = *(float4*)&sm.g.xs[ty * 4 + t][k4];
#pragma unroll
                for (int j = 0; j < 4; ++j) wv[j] = *(float4*)&sm.g.wsh[g + 16 * j][k4];
#pragma unroll
                for (int t = 0; t < 4; ++t)
#pragma unroll
                    for (int j = 0; j < 4; ++j) {
                        // k-ascending chain per output: bit-identical across rounds
                        acc[t][j] += xv[t].x * wv[j].x; acc[t][j] += xv[t].y * wv[j].y;
                        acc[t][j] += xv[t].z * wv[j].z; acc[t][j] += xv[t].w * wv[j].w;
                    }
            }
            __syncthreads();
        }

        // ---- in-block softmax: park logits tile in xs ----
#pragma unroll
        for (int t = 0; t < 4; ++t)
#pragma unroll
            for (int j = 0; j < 4; ++j)
                sm.g.xs[ty * 4 + t][g + 16 * j] = acc[t][j];
        __syncthreads();

        const int lane = tid & 63;        // lane == expert
        const int w = tid >> 6;           // wave handles tokens w*16 .. w*16+15
        float me_acc = 0.f;
#pragma unroll
        for (int it = 0; it < 16; ++it) {
            const int trow = w * 16 + it;
            float v = sm.g.xs[trow][lane];
            float m = v;
#pragma unroll
            for (int off = 32; off; off >>= 1) m = fmaxf(m, __shfl_xor(m, off));
            float ev = expf(v - m);
            float sum = ev;
#pragma unroll
            for (int off = 32; off; off >>= 1) sum += __shfl_xor(sum, off);
            float gate = ev / sum;
            me_acc += gate;

            float bv = gate; int bi = lane;
#pragma unroll
            for (int off = 32; off; off >>= 1) {
                float ov = __shfl_xor(bv, off);
                int   oi = __shfl_xor(bi, off);
                if (ov > bv || (ov == bv && oi < bi)) { bv = ov; bi = oi; }
            }
            if (lane == 0) {
                const int s = s0 + trow;
                tok_expert[s] = bi;
                tok_gate[s]   = bv;
                tok_noise[s]  = jax_uniform_noise((unsigned)(s * NEXP + bi));
            }
        }
        sm.g.mep[w][lane] = me_acc;
        __syncthreads();
        if (tid < 64)
            me_part[(size_t)bid * 64 + tid] = sm.g.mep[0][tid] + sm.g.mep[1][tid];
        __syncthreads();                  // barrier drains all stores
        if (tid == 0) { __threadfence(); atomicAdd(&ctr[0], 1u); }  // release
        return;
    }

    // ------- select / finalize roles (scheduled last; GEMM long done) -------
    wait_ctr(&ctr[0], GEMM_BLOCKS);       // expected ~0 spin iterations

    if (bid == FIN_BLOCK) {               // ---- finalize: stage to ws, exit ----
        if (tid < NEXP) sm.f.hist[tid] = 0;
        __syncthreads();
        for (int s = tid; s < S_TOK; s += 128)
            atomicAdd(&sm.f.hist[tok_expert[s]], 1);
        __syncthreads();
        if (tid < 64) {
            const int e = tid;
            float me = 0.f;
            for (int b = 0; b < GEMM_BLOCKS; ++b) me += me_part[(size_t)b * 64 + e];  // serial: bit-exact
            me /= (float)S_TOK;
            int c = sm.f.hist[e];
            ws[WS_CNTS + e] = (float)c;
            float p = me * ((float)c / (float)S_TOK);
#pragma unroll
            for (int off = 32; off; off >>= 1) p += __shfl_xor(p, off);
            if (e == 0) ws[WS_LAUX] = p * (float)NEXP;
        }
        return;
    }

    // ---- per-expert top-capacity select: stage (token, slot) lists to ws ----
    const int e = (int)bid - SEL_BASE;
    int* sel_cnt = (int*)(ws + WS_SELC);
    int* sel_tok = (int*)(ws + WS_SELT) + e * CAP;
    int* sel_loc = (int*)(ws + WS_SELL) + e * CAP;

    if (tid == 0) sm.s.n = 0;
    __syncthreads();

    for (int s = tid; s < S_TOK; s += 128) {
        if (tok_expert[s] == e) {
            int i = atomicAdd(&sm.s.n, 1);
            if (i < MAXN) { sm.s.toks[i] = s; sm.s.noi[i] = tok_noise[s]; }
        }
    }
    __syncthreads();
    int n = sm.s.n; if (n > MAXN) n = MAXN;

    // rank by noise desc, ties -> lower token index (lax.top_k stability)
    for (int i = tid; i < n; i += 128) {
        float vi = sm.s.noi[i]; int si = sm.s.toks[i];
        int r = 0;
        for (int j = 0; j < n; ++j) {
            float vj = sm.s.noi[j];
            r += (vj > vi) || (vj == vi && sm.s.toks[j] < si);
        }
        sm.s.rnk[i] = r;
    }
    __syncthreads();

    for (int i = tid; i < n; i += 128) {
        if (sm.s.rnk[i] < CAP) {
            int si = sm.s.toks[i];
            int loc = 0;  // cumsum slot among kept tokens, by token index
            for (int j = 0; j < n; ++j)
                loc += (sm.s.rnk[j] < CAP) && (sm.s.toks[j] < si);
            // kept tokens have distinct rnk < CAP -> rank is a collision-free index
            sel_tok[sm.s.rnk[i]] = si;
            sel_loc[sm.s.rnk[i]] = loc;
        }
    }
    if (tid == 0) sel_cnt[e] = (n < CAP) ? n : CAP;
}

// ---- k2: tiny tail: scatter + head/tail writes (R4/R5-verified, ~9 us) ----
__global__ __launch_bounds__(128) void moe_scatter(const float* __restrict__ ws,
                                                   float* __restrict__ d_out) {
    const int tid = threadIdx.x;
    const int e = blockIdx.x;
    const float* tok_gate = ws + WS_TGATE;

    if (e == NEXP) {
        if (tid < 64) d_out[1 + 2 * COMBINE_ELEMS + tid] = ws[WS_CNTS + tid];
        if (tid == 0) d_out[0] = ws[WS_LAUX];
        return;
    }

    const int m = ((const int*)(ws + WS_SELC))[e];
    const int* sel_tok = (const int*)(ws + WS_SELT) + e * CAP;
    const int* sel_loc = (const int*)(ws + WS_SELL) + e * CAP;
    for (int k = tid; k < m; k += 128) {
        int si  = sel_tok[k];
        int loc = sel_loc[k];
        size_t base = 1ULL + (((size_t)si * NEXP + e) * CAP + (size_t)loc);
        d_out[base] = tok_gate[si];              // combine_weights
        d_out[base + COMBINE_ELEMS] = 1.0f;      // dispatch_mask
    }
}

// ws is poisoned each iteration -> zero the gemm-done counter first.
__global__ void init_ctr(unsigned* __restrict__ ctr) {
    ctr[threadIdx.x] = 0u;
}

extern "C" void kernel_launch(void* const* d_in, const int* in_sizes, int n_in,
                              void* d_out, int out_size, void* d_ws, size_t ws_size,
                              hipStream_t stream) {
    const float* x  = (const float*)d_in[0];
    const float* wg = (const float*)d_in[1];
    float* out = (float*)d_out;
    float* ws  = (float*)d_ws;

    init_ctr<<<1, 2, 0, stream>>>((unsigned*)(ws + WS_CTR));
    moe_k1<<<TOTAL_BLOCKS, 128, 0, stream>>>(x, wg, ws, out);
    moe_scatter<<<NEXP + 1, 128, 0, stream>>>(ws, out);
}